// Round 15
// baseline (123.381 us; speedup 1.0000x reference)
//
#include <hip/hip_runtime.h>
#include <hip/hip_bf16.h>

#define B_ 2
#define N_ 8192
#define NC_ 512
#define D_ 512
#define H_ 16
#define HD_ 32
#define SCALE_ 0.17677669529663687f
#define LOG2E_ 1.4426950408889634f
#define EPS_ 1e-6f
#define NCHUNK 32
#define CHUNK (N_ / NCHUNK)   // 256 keys per chunk

typedef __attribute__((ext_vector_type(8))) short bf16x8_t;
typedef __attribute__((ext_vector_type(4))) short bf16x4_t;
typedef __attribute__((ext_vector_type(4))) float f32x4_t;

static __device__ __forceinline__ short f2bf(float f) {
    unsigned u = __float_as_uint(f);
    unsigned r = (u + 0x7FFFu + ((u >> 16) & 1u)) >> 16;
    return (short)r;
}

// native v_exp_f32 (D = 2^S0)
static __device__ __forceinline__ float fast_exp2(float x) {
#if __has_builtin(__builtin_amdgcn_exp2f)
    return __builtin_amdgcn_exp2f(x);
#else
    float r; asm("v_exp_f32 %0, %1" : "=v"(r) : "v"(x)); return r;
#endif
}

// one u32 holding two truncated bf16: low half = trunc(lo), high = trunc(hi)
static __device__ __forceinline__ unsigned pack_trunc(float lo, float hi) {
    return __builtin_amdgcn_perm(__float_as_uint(hi), __float_as_uint(lo), 0x07060302u);
}

static __device__ __forceinline__ float bf2f(short s) {
    return __uint_as_float((unsigned)(unsigned short)s << 16);
}

static __device__ __forceinline__ void gload_lds16(const short* g, void* l) {
    __builtin_amdgcn_global_load_lds(
        (const __attribute__((address_space(1))) void*)g,
        (__attribute__((address_space(3))) void*)l, 16, 0, 0);
}

// ---------------------------------------------------------------------------
// Fused prep: blocks [0,4352) convert x+clusters fp32->bf16 (8 elems/thread);
// blocks [4352,5888) transpose+convert the three weight matrices.
// ---------------------------------------------------------------------------
__global__ __launch_bounds__(256) void prep_kernel(
    const float* __restrict__ x, short* __restrict__ x_bf, int na8,
    const float* __restrict__ clusters, short* __restrict__ cl_bf,
    const float* __restrict__ Wq, const float* __restrict__ Wkv,
    const float* __restrict__ Wout,
    short* __restrict__ WqT, short* __restrict__ WkvT, short* __restrict__ WoutT)
{
    __shared__ short t[32][34];
    const int bid = blockIdx.x;
    if (bid < 4352) {
        int i8 = bid * 256 + threadIdx.x;
        const float* src; short* dst;
        if (i8 < na8) { src = x + (size_t)i8 * 8; dst = x_bf + (size_t)i8 * 8; }
        else { size_t o = (size_t)(i8 - na8) * 8; src = clusters + o; dst = cl_bf + o; }
        float4 v0 = *(const float4*)src;
        float4 v1 = *(const float4*)(src + 4);
        bf16x8_t p = {f2bf(v0.x), f2bf(v0.y), f2bf(v0.z), f2bf(v0.w),
                      f2bf(v1.x), f2bf(v1.y), f2bf(v1.z), f2bf(v1.w)};
        *(bf16x8_t*)dst = p;
        return;
    }
    const int idx = bid - 4352;
    const int bz = idx >> 9, rem = idx & 511;
    const int byy = rem >> 5, bxx = rem & 31;
    const float* src; short* dst; int ncols;
    if (bz == 0)      { src = Wq;   dst = WqT;   ncols = 512; }
    else if (bz == 1) { src = Wkv;  dst = WkvT;  ncols = 1024; }
    else              { src = Wout; dst = WoutT; ncols = 512; }
    if (bxx * 32 >= ncols) return;

    const int c0 = bxx * 32, r0 = byy * 32;
    const int tc = threadIdx.x & 31, tr = threadIdx.x >> 5;
#pragma unroll
    for (int i = 0; i < 4; i++) {
        int r = tr + i * 8;
        t[tc][r] = f2bf(src[(size_t)(r0 + r) * ncols + c0 + tc]);
    }
    __syncthreads();
#pragma unroll
    for (int i = 0; i < 4; i++) {
        int outr = tr + i * 8;
        dst[(size_t)(c0 + outr) * 512 + r0 + tc] = t[outr][tc];
    }
}

// ---------------------------------------------------------------------------
// Fused kv + q projection GEMMs. Blocks [0,1024): kv (XCD-swizzled 8x128).
// Blocks [1024,1056): q * SCALE*log2e (4x8). m97 structure, BK=64 via two
// independent [128][32] sub-buffers.
// ---------------------------------------------------------------------------
__global__ __launch_bounds__(256) void gemm_kvq_kernel(
    const short* __restrict__ x_bf, const short* __restrict__ WkvT,
    short* __restrict__ kvb,
    const short* __restrict__ cl_bf, const short* __restrict__ WqT,
    short* __restrict__ qb)
{
    __shared__ short As[2][128 * 32];
    __shared__ short Bs[2][128 * 32];

    const int tid = threadIdx.x;
    const int wid = tid >> 6, lane = tid & 63;
    const int l16 = lane & 15, lg = lane >> 4;
    const int wr = (wid >> 1) * 64, wc = (wid & 1) * 64;
    const int K = D_;

    const short* A; const short* BT; short* C; int N; float oscale; int bx, by;
    if (blockIdx.x < 1024) {
        int swz = (blockIdx.x & 7) * 128 + (blockIdx.x >> 3);   // XCD-chunked
        bx = swz & 7; by = swz >> 3;                            // grid 8 x 128
        A = x_bf; BT = WkvT; C = kvb; N = 2 * D_; oscale = 1.0f;
    } else {
        int r = blockIdx.x - 1024;
        bx = r & 3; by = r >> 2;                                // grid 4 x 8
        A = cl_bf; BT = WqT; C = qb; N = D_; oscale = SCALE_ * LOG2E_;
    }

    const f32x4_t zero4 = {0.f, 0.f, 0.f, 0.f};
    f32x4_t acc[4][4];
#pragma unroll
    for (int i = 0; i < 4; i++)
#pragma unroll
        for (int j = 0; j < 4; j++) acc[i][j] = zero4;

    const short* aptr = A + (size_t)(by * 128 + wid * 16 + (lane >> 2)) * K + (lane & 3) * 8;
    const short* bptr = BT + (size_t)(bx * 128 + wid * 16 + (lane >> 2)) * K + (lane & 3) * 8;
    char* al0 = (char*)As[0] + wid * 1024;
    char* al1 = (char*)As[1] + wid * 1024;
    char* bl0 = (char*)Bs[0] + wid * 1024;
    char* bl1 = (char*)Bs[1] + wid * 1024;
    const size_t rstep = (size_t)64 * K;

    for (int kt = 0; kt < K; kt += 64) {
        gload_lds16(aptr + kt, al0);
        gload_lds16(aptr + rstep + kt, al0 + 4096);
        gload_lds16(aptr + kt + 32, al1);
        gload_lds16(aptr + rstep + kt + 32, al1 + 4096);
        gload_lds16(bptr + kt, bl0);
        gload_lds16(bptr + rstep + kt, bl0 + 4096);
        gload_lds16(bptr + kt + 32, bl1);
        gload_lds16(bptr + rstep + kt + 32, bl1 + 4096);
        __syncthreads();

#pragma unroll
        for (int sub = 0; sub < 2; sub++) {
            bf16x8_t bfr[4];
#pragma unroll
            for (int nf = 0; nf < 4; nf++)
                bfr[nf] = *(const bf16x8_t*)&Bs[sub][(wc + nf * 16 + l16) * 32 + lg * 8];
#pragma unroll
            for (int mf = 0; mf < 4; mf++) {
                bf16x8_t afr = *(const bf16x8_t*)&As[sub][(wr + mf * 16 + l16) * 32 + lg * 8];
#pragma unroll
                for (int nf = 0; nf < 4; nf++)
                    acc[mf][nf] = __builtin_amdgcn_mfma_f32_16x16x32_bf16(
                        afr, bfr[nf], acc[mf][nf], 0, 0, 0);
            }
        }
        __syncthreads();
    }

#pragma unroll
    for (int mf = 0; mf < 4; mf++) {
#pragma unroll
        for (int nf = 0; nf < 4; nf++) {
            int row0 = by * 128 + wr + mf * 16 + lg * 4;
            int col  = bx * 128 + wc + nf * 16 + l16;
#pragma unroll
            for (int r = 0; r < 4; r++)
                C[(size_t)(row0 + r) * N + col] = f2bf(acc[mf][nf][r] * oscale);
        }
    }
}

// ---------------------------------------------------------------------------
// out = out_mid @ WoutT^T (fp32 out). m97 structure, BK=64 dual sub-buffers.
// ---------------------------------------------------------------------------
__global__ __launch_bounds__(256) void gemm_out_kernel(
    const short* __restrict__ A, const short* __restrict__ BT,
    float* __restrict__ C)
{
    __shared__ short As[2][128 * 32];
    __shared__ short Bs[2][128 * 32];

    const int tid = threadIdx.x;
    const int wid = tid >> 6, lane = tid & 63;
    const int l16 = lane & 15, lg = lane >> 4;
    const int wr = (wid >> 1) * 64, wc = (wid & 1) * 64;
    const int K = D_, N = D_;

    const int nwg = gridDim.x * gridDim.y;
    const int flat = blockIdx.y * gridDim.x + blockIdx.x;
    const int swz = (flat & 7) * (nwg >> 3) + (flat >> 3);   // nwg % 8 == 0
    const int bx = swz % gridDim.x, by = swz / gridDim.x;

    const f32x4_t zero4 = {0.f, 0.f, 0.f, 0.f};
    f32x4_t acc[4][4];
#pragma unroll
    for (int i = 0; i < 4; i++)
#pragma unroll
        for (int j = 0; j < 4; j++) acc[i][j] = zero4;

    const short* aptr = A + (size_t)(by * 128 + wid * 16 + (lane >> 2)) * K + (lane & 3) * 8;
    const short* bptr = BT + (size_t)(bx * 128 + wid * 16 + (lane >> 2)) * K + (lane & 3) * 8;
    char* al0 = (char*)As[0] + wid * 1024;
    char* al1 = (char*)As[1] + wid * 1024;
    char* bl0 = (char*)Bs[0] + wid * 1024;
    char* bl1 = (char*)Bs[1] + wid * 1024;
    const size_t rstep = (size_t)64 * K;

    for (int kt = 0; kt < K; kt += 64) {
        gload_lds16(aptr + kt, al0);
        gload_lds16(aptr + rstep + kt, al0 + 4096);
        gload_lds16(aptr + kt + 32, al1);
        gload_lds16(aptr + rstep + kt + 32, al1 + 4096);
        gload_lds16(bptr + kt, bl0);
        gload_lds16(bptr + rstep + kt, bl0 + 4096);
        gload_lds16(bptr + kt + 32, bl1);
        gload_lds16(bptr + rstep + kt + 32, bl1 + 4096);
        __syncthreads();

#pragma unroll
        for (int sub = 0; sub < 2; sub++) {
            bf16x8_t bfr[4];
#pragma unroll
            for (int nf = 0; nf < 4; nf++)
                bfr[nf] = *(const bf16x8_t*)&Bs[sub][(wc + nf * 16 + l16) * 32 + lg * 8];
#pragma unroll
            for (int mf = 0; mf < 4; mf++) {
                bf16x8_t afr = *(const bf16x8_t*)&As[sub][(wr + mf * 16 + l16) * 32 + lg * 8];
#pragma unroll
                for (int nf = 0; nf < 4; nf++)
                    acc[mf][nf] = __builtin_amdgcn_mfma_f32_16x16x32_bf16(
                        afr, bfr[nf], acc[mf][nf], 0, 0, 0);
            }
        }
        __syncthreads();
    }

#pragma unroll
    for (int mf = 0; mf < 4; mf++) {
#pragma unroll
        for (int nf = 0; nf < 4; nf++) {
            int row0 = by * 128 + wr + mf * 16 + lg * 4;
            int col  = bx * 128 + wc + nf * 16 + l16;
#pragma unroll
            for (int r = 0; r < 4; r++)
                C[(size_t)(row0 + r) * N + col] = acc[mf][nf][r];
        }
    }
}

// ---------------------------------------------------------------------------
// Attention, 8-wave variant: block = (chunk, h, b); 8 waves x 64 cluster
// rows (512 threads) — halves per-wave state (VGPR) and per-barrier mf
// chains vs the 4-wave version, raising waves/SIMD for latency hiding.
// Same algorithm as round-9: P_lds holds UNNORMALIZED e (same-wave use,
// 2-bit 16B-unit swizzle); colsum in-reg + 2 shfl into reds[.][8][32];
// ONE barrier/tile; inv folded into V (V'=inv*V) and ts B-frag (= inv).
// K/V prefetched one tile ahead; V staged by threads 0..255 only.
// ---------------------------------------------------------------------------
__global__ __launch_bounds__(512) void attn_kernel(
    const short* __restrict__ qb,    // [B*NC][D] bf16 (pre-scaled)
    const short* __restrict__ kvb,   // [B*N][2D] bf16
    short* __restrict__ out_part,    // [NCHUNK][B][H][NC][HD] bf16
    float* __restrict__ ts_part)     // [NCHUNK][B][H][NC]
{
    const int chunk = blockIdx.x, h = blockIdx.y, b = blockIdx.z;
    const int tid = threadIdx.x, wid = tid >> 6, lane = tid & 63;
    const int l16 = lane & 15, lg = lane >> 4;

    __shared__ short P_lds[512 * 32];     // swizzled, 32 KB (same-wave use only)
    __shared__ short v_t[2][32][40];      // [buf][d][key], double-buffered
    __shared__ float reds[2][8][32];      // [buf][wave][key] column-sum partials

    bf16x8_t qf[4];
#pragma unroll
    for (int mf = 0; mf < 4; mf++) {
        int row = wid * 64 + mf * 16 + l16;
        qf[mf] = *(const bf16x8_t*)&qb[(size_t)(b * NC_ + row) * D_ + h * HD_ + lg * 8];
    }

    const f32x4_t zero4 = {0.f, 0.f, 0.f, 0.f};
    f32x4_t oacc[4][2], tsacc[4];
#pragma unroll
    for (int mf = 0; mf < 4; mf++) {
        oacc[mf][0] = zero4; oacc[mf][1] = zero4; tsacc[mf] = zero4;
    }

    const short* kptr = kvb + (size_t)(b * N_ + chunk * CHUNK + l16) * (2 * D_) + h * HD_ + lg * 8;
    const int skey = (tid & 255) >> 3, sd0 = (tid & 7) * 4;
    const short* vptr = kvb + (size_t)(b * N_ + chunk * CHUNK + skey) * (2 * D_) + D_ + h * HD_ + sd0;
    char* Pb = (char*)P_lds;

    // prologue: prefetch tile 0's K halves and V
    bf16x8_t kf0 = *(const bf16x8_t*)(kptr);
    bf16x8_t kf1 = *(const bf16x8_t*)(kptr + 16 * (2 * D_));
    bf16x4_t vv  = *(const bf16x4_t*)(vptr);

    for (int kt = 0; kt < CHUNK / 32; kt++) {
        const int cur = kt & 1;

        // stage this tile's V (prefetched last iteration); threads 0..255
        if (tid < 256) {
            v_t[cur][sd0 + 0][skey] = vv[0];
            v_t[cur][sd0 + 1][skey] = vv[1];
            v_t[cur][sd0 + 2][skey] = vv[2];
            v_t[cur][sd0 + 3][skey] = vv[3];
        }

#pragma unroll
        for (int half = 0; half < 2; half++) {
            f32x4_t s[4];
            bf16x8_t kf = half ? kf1 : kf0;
#pragma unroll
            for (int mf = 0; mf < 4; mf++)
                s[mf] = __builtin_amdgcn_mfma_f32_16x16x32_bf16(qf[mf], kf, zero4, 0, 0, 0);

            // exp, write UNNORMALIZED e to P_lds, accumulate column sum
            const int kbyte = (l16 & 7) * 2;
            const int ku = (l16 >> 3) + half * 2;
            float sl = 0.f;
#pragma unroll
            for (int mf = 0; mf < 4; mf++) {
#pragma unroll
                for (int r = 0; r < 4; r++) {
                    float e = fast_exp2(s[mf][r]);
                    sl += e;
                    int row = wid * 64 + mf * 16 + lg * 4 + r;
                    int x = (row >> 1) & 3;
                    *(short*)(Pb + row * 64 + kbyte + (((ku ^ x) & 3) << 4)) =
                        (short)(__float_as_uint(e) >> 16);
                }
            }
            sl += __shfl_xor(sl, 16, 64);
            sl += __shfl_xor(sl, 32, 64);
            if (lane < 16) reds[cur][wid][half * 16 + lane] = sl;
        }

        // prefetch next tile's K/V (wraps harmlessly on last tile)
        {
            const size_t koffn = (size_t)((kt + 1) & (CHUNK / 32 - 1)) * 32 * (2 * D_);
            kf0 = *(const bf16x8_t*)(kptr + koffn);
            kf1 = *(const bf16x8_t*)(kptr + koffn + 16 * (2 * D_));
            vv  = *(const bf16x4_t*)(vptr + koffn);
        }

        __syncthreads();   // reds + v_t ready; P_lds is same-wave only

        // per-lane totals for keys lg*8..lg*8+7 (sum over 8 wave partials)
        f32x4_t ta = *(const f32x4_t*)&reds[cur][0][lg * 8];
        f32x4_t tb = *(const f32x4_t*)&reds[cur][0][lg * 8 + 4];
#pragma unroll
        for (int w = 1; w < 8; w++) {
            ta += *(const f32x4_t*)&reds[cur][w][lg * 8];
            tb += *(const f32x4_t*)&reds[cur][w][lg * 8 + 4];
        }
        float iv[8];
#pragma unroll
        for (int r = 0; r < 4; r++) {
            iv[r]     = __fdividef(1.f, ta[r]);
            iv[4 + r] = __fdividef(1.f, tb[r]);
        }

        // scale V fragments by inv[key] and build ts B-frag (= inv)
        bf16x8_t v0r = *(const bf16x8_t*)&v_t[cur][l16][lg * 8];
        bf16x8_t v1r = *(const bf16x8_t*)&v_t[cur][16 + l16][lg * 8];
        bf16x8_t v0, v1, invf;
        {
            unsigned* p0 = (unsigned*)&v0;
            unsigned* p1 = (unsigned*)&v1;
            unsigned* pi = (unsigned*)&invf;
#pragma unroll
            for (int j = 0; j < 4; j++) {
                float a0 = bf2f(v0r[2 * j])     * iv[2 * j];
                float a1 = bf2f(v0r[2 * j + 1]) * iv[2 * j + 1];
                float b0 = bf2f(v1r[2 * j])     * iv[2 * j];
                float b1 = bf2f(v1r[2 * j + 1]) * iv[2 * j + 1];
                p0[j] = pack_trunc(a0, a1);
                p1[j] = pack_trunc(b0, b1);
                pi[j] = pack_trunc(iv[2 * j], iv[2 * j + 1]);
            }
        }

        // PV + ts (reads own wave's P rows; same-wave DS ordering)
#pragma unroll
        for (int mf = 0; mf < 4; mf++) {
            int row = wid * 64 + mf * 16 + l16;
            bf16x8_t pa = *(const bf16x8_t*)(Pb + row * 64 +
                              (((lg ^ ((row >> 1) & 3)) & 3) << 4));
            oacc[mf][0] = __builtin_amdgcn_mfma_f32_16x16x32_bf16(pa, v0, oacc[mf][0], 0, 0, 0);
            oacc[mf][1] = __builtin_amdgcn_mfma_f32_16x16x32_bf16(pa, v1, oacc[mf][1], 0, 0, 0);
            tsacc[mf]   = __builtin_amdgcn_mfma_f32_16x16x32_bf16(pa, invf, tsacc[mf], 0, 0, 0);
        }
    }

    const size_t base = ((size_t)(chunk * B_ + b) * H_ + h);
#pragma unroll
    for (int mf = 0; mf < 4; mf++) {
        int row0 = wid * 64 + mf * 16 + lg * 4;
#pragma unroll
        for (int nf = 0; nf < 2; nf++) {
            int col = nf * 16 + l16;
#pragma unroll
            for (int r = 0; r < 4; r++)
                out_part[(base * NC_ + row0 + r) * HD_ + col] = f2bf(oacc[mf][nf][r]);
        }
        if (l16 == 0) {
#pragma unroll
            for (int r = 0; r < 4; r++)
                ts_part[base * NC_ + row0 + r] = tsacc[mf][r];
        }
    }
}

// ---------------------------------------------------------------------------
// Reduce chunk partials (bf16), apply /(ts+eps), emit token_sizes + out_mid.
// ---------------------------------------------------------------------------
__global__ __launch_bounds__(256) void reduce_kernel(
    const short* __restrict__ out_part, const float* __restrict__ ts_part,
    short* __restrict__ out_mid, float* __restrict__ tok_out)
{
    const int bnc = blockIdx.x;
    const int b = bnc >> 9, nc = bnc & 511;
    const int t = threadIdx.x;
    __shared__ float tsh[16];
    if (t < 16) {
        float s = 0.f;
#pragma unroll
        for (int ch = 0; ch < NCHUNK; ch++)
            s += ts_part[((size_t)(ch * B_ + b) * H_ + t) * NC_ + nc];
        tsh[t] = s;
    }
    __syncthreads();
    if (t == 0) {
        float s = 0.f;
#pragma unroll
        for (int i = 0; i < 16; i++) s += tsh[i];
        tok_out[b * NC_ + nc] = s * (1.f / 16.f);
    }
    for (int c = t; c < D_; c += 256) {
        int hh = c >> 5, d = c & 31;
        float s = 0.f;
#pragma unroll
        for (int ch = 0; ch < NCHUNK; ch++) {
            unsigned short u = (unsigned short)
                out_part[(((size_t)(ch * B_ + b) * H_ + hh) * NC_ + nc) * HD_ + d];
            s += __uint_as_float((unsigned)u << 16);
        }
        out_mid[(size_t)(b * NC_ + nc) * D_ + c] = f2bf(s / (tsh[hh] + EPS_));
    }
}

// ---------------------------------------------------------------------------
extern "C" void kernel_launch(void* const* d_in, const int* in_sizes, int n_in,
                              void* d_out, int out_size, void* d_ws, size_t ws_size,
                              hipStream_t stream)
{
    (void)in_sizes; (void)n_in; (void)out_size; (void)ws_size;
    const float* x        = (const float*)d_in[0];
    const float* clusters = (const float*)d_in[1];
    const float* Wq       = (const float*)d_in[2];
    const float* Wkv      = (const float*)d_in[3];
    const float* Wout     = (const float*)d_in[4];

    char* ws = (char*)d_ws;
    short* x_bf     = (short*)(ws);                 // 16,777,216 [dead after kv gemm]
    short* WkvT     = (short*)(ws + 16777216);      //  1,048,576 [dead after kv gemm]
    short* cl_bf    = (short*)(ws + 17825792);      //  1,048,576 [dead after q gemm]
    short* WqT      = (short*)(ws + 18874368);      //    524,288 [dead after q gemm]
    short* out_part = (short*)(ws);                 // 33,554,432 bf16 [attn, over dead]
    float* ts_part  = (float*)(ws + 33554432);      //  2,097,152
    short* kvb      = (short*)(ws + 35651584);      // 33,554,432 [dead after attn]
    short* out_mid  = (short*)(ws + 35651584);      //  1,048,576 [reduce, over kvb]
    short* qb       = (short*)(ws + 69206016);      //  1,048,576
    short* WoutT    = (short*)(ws + 70254592);      //    524,288
    // total 70,778,880 bytes

    float* out = (float*)d_out;
    float* tok = out + (size_t)B_ * NC_ * D_;

    // 1. fused convert (x, clusters) + weight transpose
    prep_kernel<<<dim3(5888), dim3(256), 0, stream>>>(
        x, x_bf, (B_ * N_ * D_) / 8, clusters, cl_bf,
        Wq, Wkv, Wout, WqT, WkvT, WoutT);
    // 2. fused kv + q projections (q rides the kv tail)
    gemm_kvq_kernel<<<dim3(1056), dim3(256), 0, stream>>>(
        x_bf, WkvT, kvb, cl_bf, WqT, qb);
    // 3. attention partials (8 waves x 64 rows)
    attn_kernel<<<dim3(NCHUNK, H_, B_), dim3(512), 0, stream>>>(
        qb, kvb, out_part, ts_part);
    // 4. reduce + normalize + token_sizes
    reduce_kernel<<<dim3(B_ * NC_), dim3(256), 0, stream>>>(
        out_part, ts_part, out_mid, tok);
    // 5. out = out_mid @ Wout (fp32)
    gemm_out_kernel<<<dim3(D_ / 128, (B_ * NC_) / 128), dim3(256), 0, stream>>>(
        out_mid, WoutT, (float*)d_out);
}

// Round 16
// 118.690 us; speedup vs baseline: 1.0395x; 1.0395x over previous
//
#include <hip/hip_runtime.h>
#include <hip/hip_bf16.h>

#define B_ 2
#define N_ 8192
#define NC_ 512
#define D_ 512
#define H_ 16
#define HD_ 32
#define SCALE_ 0.17677669529663687f
#define LOG2E_ 1.4426950408889634f
#define EPS_ 1e-6f
#define NCHUNK 32
#define CHUNK (N_ / NCHUNK)   // 256 keys per chunk

typedef __attribute__((ext_vector_type(8))) short bf16x8_t;
typedef __attribute__((ext_vector_type(4))) short bf16x4_t;
typedef __attribute__((ext_vector_type(4))) float f32x4_t;

static __device__ __forceinline__ short f2bf(float f) {
    unsigned u = __float_as_uint(f);
    unsigned r = (u + 0x7FFFu + ((u >> 16) & 1u)) >> 16;
    return (short)r;
}

// native v_exp_f32 (D = 2^S0)
static __device__ __forceinline__ float fast_exp2(float x) {
#if __has_builtin(__builtin_amdgcn_exp2f)
    return __builtin_amdgcn_exp2f(x);
#else
    float r; asm("v_exp_f32 %0, %1" : "=v"(r) : "v"(x)); return r;
#endif
}

// one u32 holding two truncated bf16: low half = trunc(lo), high = trunc(hi)
static __device__ __forceinline__ unsigned pack_trunc(float lo, float hi) {
    return __builtin_amdgcn_perm(__float_as_uint(hi), __float_as_uint(lo), 0x07060302u);
}

static __device__ __forceinline__ float bf2f(short s) {
    return __uint_as_float((unsigned)(unsigned short)s << 16);
}

static __device__ __forceinline__ void gload_lds16(const short* g, void* l) {
    __builtin_amdgcn_global_load_lds(
        (const __attribute__((address_space(1))) void*)g,
        (__attribute__((address_space(3))) void*)l, 16, 0, 0);
}

// ---------------------------------------------------------------------------
// Fused prep: blocks [0,4352) convert x+clusters fp32->bf16 (8 elems/thread);
// blocks [4352,5888) transpose+convert the three weight matrices.
// ---------------------------------------------------------------------------
__global__ __launch_bounds__(256) void prep_kernel(
    const float* __restrict__ x, short* __restrict__ x_bf, int na8,
    const float* __restrict__ clusters, short* __restrict__ cl_bf,
    const float* __restrict__ Wq, const float* __restrict__ Wkv,
    const float* __restrict__ Wout,
    short* __restrict__ WqT, short* __restrict__ WkvT, short* __restrict__ WoutT)
{
    __shared__ short t[32][34];
    const int bid = blockIdx.x;
    if (bid < 4352) {
        int i8 = bid * 256 + threadIdx.x;
        const float* src; short* dst;
        if (i8 < na8) { src = x + (size_t)i8 * 8; dst = x_bf + (size_t)i8 * 8; }
        else { size_t o = (size_t)(i8 - na8) * 8; src = clusters + o; dst = cl_bf + o; }
        float4 v0 = *(const float4*)src;
        float4 v1 = *(const float4*)(src + 4);
        bf16x8_t p = {f2bf(v0.x), f2bf(v0.y), f2bf(v0.z), f2bf(v0.w),
                      f2bf(v1.x), f2bf(v1.y), f2bf(v1.z), f2bf(v1.w)};
        *(bf16x8_t*)dst = p;
        return;
    }
    const int idx = bid - 4352;
    const int bz = idx >> 9, rem = idx & 511;
    const int byy = rem >> 5, bxx = rem & 31;
    const float* src; short* dst; int ncols;
    if (bz == 0)      { src = Wq;   dst = WqT;   ncols = 512; }
    else if (bz == 1) { src = Wkv;  dst = WkvT;  ncols = 1024; }
    else              { src = Wout; dst = WoutT; ncols = 512; }
    if (bxx * 32 >= ncols) return;

    const int c0 = bxx * 32, r0 = byy * 32;
    const int tc = threadIdx.x & 31, tr = threadIdx.x >> 5;
#pragma unroll
    for (int i = 0; i < 4; i++) {
        int r = tr + i * 8;
        t[tc][r] = f2bf(src[(size_t)(r0 + r) * ncols + c0 + tc]);
    }
    __syncthreads();
#pragma unroll
    for (int i = 0; i < 4; i++) {
        int outr = tr + i * 8;
        dst[(size_t)(c0 + outr) * 512 + r0 + tc] = t[outr][tc];
    }
}

// ---------------------------------------------------------------------------
// Fused kv + q projection GEMMs. Blocks [0,1024): kv (XCD-swizzled 8x128).
// Blocks [1024,1056): q * SCALE*log2e (4x8). m97 structure, BK=64 via two
// independent [128][32] sub-buffers.
// ---------------------------------------------------------------------------
__global__ __launch_bounds__(256) void gemm_kvq_kernel(
    const short* __restrict__ x_bf, const short* __restrict__ WkvT,
    short* __restrict__ kvb,
    const short* __restrict__ cl_bf, const short* __restrict__ WqT,
    short* __restrict__ qb)
{
    __shared__ short As[2][128 * 32];
    __shared__ short Bs[2][128 * 32];

    const int tid = threadIdx.x;
    const int wid = tid >> 6, lane = tid & 63;
    const int l16 = lane & 15, lg = lane >> 4;
    const int wr = (wid >> 1) * 64, wc = (wid & 1) * 64;
    const int K = D_;

    const short* A; const short* BT; short* C; int N; float oscale; int bx, by;
    if (blockIdx.x < 1024) {
        int swz = (blockIdx.x & 7) * 128 + (blockIdx.x >> 3);   // XCD-chunked
        bx = swz & 7; by = swz >> 3;                            // grid 8 x 128
        A = x_bf; BT = WkvT; C = kvb; N = 2 * D_; oscale = 1.0f;
    } else {
        int r = blockIdx.x - 1024;
        bx = r & 3; by = r >> 2;                                // grid 4 x 8
        A = cl_bf; BT = WqT; C = qb; N = D_; oscale = SCALE_ * LOG2E_;
    }

    const f32x4_t zero4 = {0.f, 0.f, 0.f, 0.f};
    f32x4_t acc[4][4];
#pragma unroll
    for (int i = 0; i < 4; i++)
#pragma unroll
        for (int j = 0; j < 4; j++) acc[i][j] = zero4;

    const short* aptr = A + (size_t)(by * 128 + wid * 16 + (lane >> 2)) * K + (lane & 3) * 8;
    const short* bptr = BT + (size_t)(bx * 128 + wid * 16 + (lane >> 2)) * K + (lane & 3) * 8;
    char* al0 = (char*)As[0] + wid * 1024;
    char* al1 = (char*)As[1] + wid * 1024;
    char* bl0 = (char*)Bs[0] + wid * 1024;
    char* bl1 = (char*)Bs[1] + wid * 1024;
    const size_t rstep = (size_t)64 * K;

    for (int kt = 0; kt < K; kt += 64) {
        gload_lds16(aptr + kt, al0);
        gload_lds16(aptr + rstep + kt, al0 + 4096);
        gload_lds16(aptr + kt + 32, al1);
        gload_lds16(aptr + rstep + kt + 32, al1 + 4096);
        gload_lds16(bptr + kt, bl0);
        gload_lds16(bptr + rstep + kt, bl0 + 4096);
        gload_lds16(bptr + kt + 32, bl1);
        gload_lds16(bptr + rstep + kt + 32, bl1 + 4096);
        __syncthreads();

#pragma unroll
        for (int sub = 0; sub < 2; sub++) {
            bf16x8_t bfr[4];
#pragma unroll
            for (int nf = 0; nf < 4; nf++)
                bfr[nf] = *(const bf16x8_t*)&Bs[sub][(wc + nf * 16 + l16) * 32 + lg * 8];
#pragma unroll
            for (int mf = 0; mf < 4; mf++) {
                bf16x8_t afr = *(const bf16x8_t*)&As[sub][(wr + mf * 16 + l16) * 32 + lg * 8];
#pragma unroll
                for (int nf = 0; nf < 4; nf++)
                    acc[mf][nf] = __builtin_amdgcn_mfma_f32_16x16x32_bf16(
                        afr, bfr[nf], acc[mf][nf], 0, 0, 0);
            }
        }
        __syncthreads();
    }

#pragma unroll
    for (int mf = 0; mf < 4; mf++) {
#pragma unroll
        for (int nf = 0; nf < 4; nf++) {
            int row0 = by * 128 + wr + mf * 16 + lg * 4;
            int col  = bx * 128 + wc + nf * 16 + l16;
#pragma unroll
            for (int r = 0; r < 4; r++)
                C[(size_t)(row0 + r) * N + col] = f2bf(acc[mf][nf][r] * oscale);
        }
    }
}

// ---------------------------------------------------------------------------
// out = out_mid @ WoutT^T (fp32 out). m97 structure, BK=64 dual sub-buffers.
// ---------------------------------------------------------------------------
__global__ __launch_bounds__(256) void gemm_out_kernel(
    const short* __restrict__ A, const short* __restrict__ BT,
    float* __restrict__ C)
{
    __shared__ short As[2][128 * 32];
    __shared__ short Bs[2][128 * 32];

    const int tid = threadIdx.x;
    const int wid = tid >> 6, lane = tid & 63;
    const int l16 = lane & 15, lg = lane >> 4;
    const int wr = (wid >> 1) * 64, wc = (wid & 1) * 64;
    const int K = D_, N = D_;

    const int nwg = gridDim.x * gridDim.y;
    const int flat = blockIdx.y * gridDim.x + blockIdx.x;
    const int swz = (flat & 7) * (nwg >> 3) + (flat >> 3);   // nwg % 8 == 0
    const int bx = swz % gridDim.x, by = swz / gridDim.x;

    const f32x4_t zero4 = {0.f, 0.f, 0.f, 0.f};
    f32x4_t acc[4][4];
#pragma unroll
    for (int i = 0; i < 4; i++)
#pragma unroll
        for (int j = 0; j < 4; j++) acc[i][j] = zero4;

    const short* aptr = A + (size_t)(by * 128 + wid * 16 + (lane >> 2)) * K + (lane & 3) * 8;
    const short* bptr = BT + (size_t)(bx * 128 + wid * 16 + (lane >> 2)) * K + (lane & 3) * 8;
    char* al0 = (char*)As[0] + wid * 1024;
    char* al1 = (char*)As[1] + wid * 1024;
    char* bl0 = (char*)Bs[0] + wid * 1024;
    char* bl1 = (char*)Bs[1] + wid * 1024;
    const size_t rstep = (size_t)64 * K;

    for (int kt = 0; kt < K; kt += 64) {
        gload_lds16(aptr + kt, al0);
        gload_lds16(aptr + rstep + kt, al0 + 4096);
        gload_lds16(aptr + kt + 32, al1);
        gload_lds16(aptr + rstep + kt + 32, al1 + 4096);
        gload_lds16(bptr + kt, bl0);
        gload_lds16(bptr + rstep + kt, bl0 + 4096);
        gload_lds16(bptr + kt + 32, bl1);
        gload_lds16(bptr + rstep + kt + 32, bl1 + 4096);
        __syncthreads();

#pragma unroll
        for (int sub = 0; sub < 2; sub++) {
            bf16x8_t bfr[4];
#pragma unroll
            for (int nf = 0; nf < 4; nf++)
                bfr[nf] = *(const bf16x8_t*)&Bs[sub][(wc + nf * 16 + l16) * 32 + lg * 8];
#pragma unroll
            for (int mf = 0; mf < 4; mf++) {
                bf16x8_t afr = *(const bf16x8_t*)&As[sub][(wr + mf * 16 + l16) * 32 + lg * 8];
#pragma unroll
                for (int nf = 0; nf < 4; nf++)
                    acc[mf][nf] = __builtin_amdgcn_mfma_f32_16x16x32_bf16(
                        afr, bfr[nf], acc[mf][nf], 0, 0, 0);
            }
        }
        __syncthreads();
    }

#pragma unroll
    for (int mf = 0; mf < 4; mf++) {
#pragma unroll
        for (int nf = 0; nf < 4; nf++) {
            int row0 = by * 128 + wr + mf * 16 + lg * 4;
            int col  = bx * 128 + wc + nf * 16 + l16;
#pragma unroll
            for (int r = 0; r < 4; r++)
                C[(size_t)(row0 + r) * N + col] = acc[mf][nf][r];
        }
    }
}

// ---------------------------------------------------------------------------
// Attention (round-12 kernel verbatim — best measured, 55.6 us): per-key
// normalization folded into V. block = (chunk, h, b); 4 waves x 128 cluster
// rows; 32-key tiles. P_lds holds UNNORMALIZED e (same-wave use, 2-bit
// 16B-unit swizzle). Scalar colsum via in-reg+2-shfl reduce into reds; ONE
// barrier/tile; after it each lane builds inv[k] for its 8 keys and scales
// V (V'=inv*V) and the ts B-frag (= inv). K/V prefetched one tile ahead.
// ---------------------------------------------------------------------------
__global__ __launch_bounds__(256) void attn_kernel(
    const short* __restrict__ qb,    // [B*NC][D] bf16 (pre-scaled)
    const short* __restrict__ kvb,   // [B*N][2D] bf16
    short* __restrict__ out_part,    // [NCHUNK][B][H][NC][HD] bf16
    float* __restrict__ ts_part)     // [NCHUNK][B][H][NC]
{
    const int chunk = blockIdx.x, h = blockIdx.y, b = blockIdx.z;
    const int tid = threadIdx.x, wid = tid >> 6, lane = tid & 63;
    const int l16 = lane & 15, lg = lane >> 4;

    __shared__ short P_lds[512 * 32];     // swizzled, 32 KB (same-wave use only)
    __shared__ short v_t[2][32][40];      // [buf][d][key], double-buffered
    __shared__ float reds[2][4][32];      // [buf][wave][key] column-sum partials

    bf16x8_t qf[8];
#pragma unroll
    for (int mf = 0; mf < 8; mf++) {
        int row = wid * 128 + mf * 16 + l16;
        qf[mf] = *(const bf16x8_t*)&qb[(size_t)(b * NC_ + row) * D_ + h * HD_ + lg * 8];
    }

    const f32x4_t zero4 = {0.f, 0.f, 0.f, 0.f};
    f32x4_t oacc[8][2], tsacc[8];
#pragma unroll
    for (int mf = 0; mf < 8; mf++) {
        oacc[mf][0] = zero4; oacc[mf][1] = zero4; tsacc[mf] = zero4;
    }

    const short* kptr = kvb + (size_t)(b * N_ + chunk * CHUNK + l16) * (2 * D_) + h * HD_ + lg * 8;
    const int skey = tid >> 3, sd0 = (tid & 7) * 4;
    const short* vptr = kvb + (size_t)(b * N_ + chunk * CHUNK + skey) * (2 * D_) + D_ + h * HD_ + sd0;
    char* Pb = (char*)P_lds;

    // prologue: prefetch tile 0's K halves and V
    bf16x8_t kf0 = *(const bf16x8_t*)(kptr);
    bf16x8_t kf1 = *(const bf16x8_t*)(kptr + 16 * (2 * D_));
    bf16x4_t vv  = *(const bf16x4_t*)(vptr);

    for (int kt = 0; kt < CHUNK / 32; kt++) {
        const int cur = kt & 1;

        // stage this tile's V (prefetched last iteration)
        v_t[cur][sd0 + 0][skey] = vv[0];
        v_t[cur][sd0 + 1][skey] = vv[1];
        v_t[cur][sd0 + 2][skey] = vv[2];
        v_t[cur][sd0 + 3][skey] = vv[3];

#pragma unroll
        for (int half = 0; half < 2; half++) {
            f32x4_t s[8];
            bf16x8_t kf = half ? kf1 : kf0;
#pragma unroll
            for (int mf = 0; mf < 8; mf++)
                s[mf] = __builtin_amdgcn_mfma_f32_16x16x32_bf16(qf[mf], kf, zero4, 0, 0, 0);

            // exp, write UNNORMALIZED e to P_lds, accumulate column sum
            const int kbyte = (l16 & 7) * 2;
            const int ku = (l16 >> 3) + half * 2;
            float sl = 0.f;
#pragma unroll
            for (int mf = 0; mf < 8; mf++) {
#pragma unroll
                for (int r = 0; r < 4; r++) {
                    float e = fast_exp2(s[mf][r]);
                    sl += e;
                    int row = wid * 128 + mf * 16 + lg * 4 + r;
                    int x = (row >> 1) & 3;
                    *(short*)(Pb + row * 64 + kbyte + (((ku ^ x) & 3) << 4)) =
                        (short)(__float_as_uint(e) >> 16);
                }
            }
            sl += __shfl_xor(sl, 16, 64);
            sl += __shfl_xor(sl, 32, 64);
            if (lane < 16) reds[cur][wid][half * 16 + lane] = sl;
        }

        // prefetch next tile's K/V (wraps harmlessly on last tile)
        {
            const size_t koffn = (size_t)((kt + 1) & (CHUNK / 32 - 1)) * 32 * (2 * D_);
            kf0 = *(const bf16x8_t*)(kptr + koffn);
            kf1 = *(const bf16x8_t*)(kptr + koffn + 16 * (2 * D_));
            vv  = *(const bf16x4_t*)(vptr + koffn);
        }

        __syncthreads();   // reds + v_t ready; P_lds is same-wave only

        // per-lane totals for keys lg*8..lg*8+7
        f32x4_t ta = *(const f32x4_t*)&reds[cur][0][lg * 8];
        f32x4_t tb = *(const f32x4_t*)&reds[cur][0][lg * 8 + 4];
#pragma unroll
        for (int w = 1; w < 4; w++) {
            ta += *(const f32x4_t*)&reds[cur][w][lg * 8];
            tb += *(const f32x4_t*)&reds[cur][w][lg * 8 + 4];
        }
        float iv[8];
#pragma unroll
        for (int r = 0; r < 4; r++) {
            iv[r]     = __fdividef(1.f, ta[r]);
            iv[4 + r] = __fdividef(1.f, tb[r]);
        }

        // scale V fragments by inv[key] and build ts B-frag (= inv)
        bf16x8_t v0r = *(const bf16x8_t*)&v_t[cur][l16][lg * 8];
        bf16x8_t v1r = *(const bf16x8_t*)&v_t[cur][16 + l16][lg * 8];
        bf16x8_t v0, v1, invf;
        {
            unsigned* p0 = (unsigned*)&v0;
            unsigned* p1 = (unsigned*)&v1;
            unsigned* pi = (unsigned*)&invf;
#pragma unroll
            for (int j = 0; j < 4; j++) {
                float a0 = bf2f(v0r[2 * j])     * iv[2 * j];
                float a1 = bf2f(v0r[2 * j + 1]) * iv[2 * j + 1];
                float b0 = bf2f(v1r[2 * j])     * iv[2 * j];
                float b1 = bf2f(v1r[2 * j + 1]) * iv[2 * j + 1];
                p0[j] = pack_trunc(a0, a1);
                p1[j] = pack_trunc(b0, b1);
                pi[j] = pack_trunc(iv[2 * j], iv[2 * j + 1]);
            }
        }

        // PV + ts (reads own wave's P rows; same-wave DS ordering)
#pragma unroll
        for (int mf = 0; mf < 8; mf++) {
            int row = wid * 128 + mf * 16 + l16;
            bf16x8_t pa = *(const bf16x8_t*)(Pb + row * 64 +
                              (((lg ^ ((row >> 1) & 3)) & 3) << 4));
            oacc[mf][0] = __builtin_amdgcn_mfma_f32_16x16x32_bf16(pa, v0, oacc[mf][0], 0, 0, 0);
            oacc[mf][1] = __builtin_amdgcn_mfma_f32_16x16x32_bf16(pa, v1, oacc[mf][1], 0, 0, 0);
            tsacc[mf]   = __builtin_amdgcn_mfma_f32_16x16x32_bf16(pa, invf, tsacc[mf], 0, 0, 0);
        }
    }

    const size_t base = ((size_t)(chunk * B_ + b) * H_ + h);
#pragma unroll
    for (int mf = 0; mf < 8; mf++) {
        int row0 = wid * 128 + mf * 16 + lg * 4;
#pragma unroll
        for (int nf = 0; nf < 2; nf++) {
            int col = nf * 16 + l16;
#pragma unroll
            for (int r = 0; r < 4; r++)
                out_part[(base * NC_ + row0 + r) * HD_ + col] = f2bf(oacc[mf][nf][r]);
        }
        if (l16 == 0) {
#pragma unroll
            for (int r = 0; r < 4; r++)
                ts_part[base * NC_ + row0 + r] = tsacc[mf][r];
        }
    }
}

// ---------------------------------------------------------------------------
// Reduce chunk partials (bf16), apply /(ts+eps), emit token_sizes + out_mid.
// ---------------------------------------------------------------------------
__global__ __launch_bounds__(256) void reduce_kernel(
    const short* __restrict__ out_part, const float* __restrict__ ts_part,
    short* __restrict__ out_mid, float* __restrict__ tok_out)
{
    const int bnc = blockIdx.x;
    const int b = bnc >> 9, nc = bnc & 511;
    const int t = threadIdx.x;
    __shared__ float tsh[16];
    if (t < 16) {
        float s = 0.f;
#pragma unroll
        for (int ch = 0; ch < NCHUNK; ch++)
            s += ts_part[((size_t)(ch * B_ + b) * H_ + t) * NC_ + nc];
        tsh[t] = s;
    }
    __syncthreads();
    if (t == 0) {
        float s = 0.f;
#pragma unroll
        for (int i = 0; i < 16; i++) s += tsh[i];
        tok_out[b * NC_ + nc] = s * (1.f / 16.f);
    }
    for (int c = t; c < D_; c += 256) {
        int hh = c >> 5, d = c & 31;
        float s = 0.f;
#pragma unroll
        for (int ch = 0; ch < NCHUNK; ch++) {
            unsigned short u = (unsigned short)
                out_part[(((size_t)(ch * B_ + b) * H_ + hh) * NC_ + nc) * HD_ + d];
            s += __uint_as_float((unsigned)u << 16);
        }
        out_mid[(size_t)(b * NC_ + nc) * D_ + c] = f2bf(s / (tsh[hh] + EPS_));
    }
}

// ---------------------------------------------------------------------------
extern "C" void kernel_launch(void* const* d_in, const int* in_sizes, int n_in,
                              void* d_out, int out_size, void* d_ws, size_t ws_size,
                              hipStream_t stream)
{
    (void)in_sizes; (void)n_in; (void)out_size; (void)ws_size;
    const float* x        = (const float*)d_in[0];
    const float* clusters = (const float*)d_in[1];
    const float* Wq       = (const float*)d_in[2];
    const float* Wkv      = (const float*)d_in[3];
    const float* Wout     = (const float*)d_in[4];

    char* ws = (char*)d_ws;
    short* x_bf     = (short*)(ws);                 // 16,777,216 [dead after kv gemm]
    short* WkvT     = (short*)(ws + 16777216);      //  1,048,576 [dead after kv gemm]
    short* cl_bf    = (short*)(ws + 17825792);      //  1,048,576 [dead after q gemm]
    short* WqT      = (short*)(ws + 18874368);      //    524,288 [dead after q gemm]
    short* out_part = (short*)(ws);                 // 33,554,432 bf16 [attn, over dead]
    float* ts_part  = (float*)(ws + 33554432);      //  2,097,152
    short* kvb      = (short*)(ws + 35651584);      // 33,554,432 [dead after attn]
    short* out_mid  = (short*)(ws + 35651584);      //  1,048,576 [reduce, over kvb]
    short* qb       = (short*)(ws + 69206016);      //  1,048,576
    short* WoutT    = (short*)(ws + 70254592);      //    524,288
    // total 70,778,880 bytes

    float* out = (float*)d_out;
    float* tok = out + (size_t)B_ * NC_ * D_;

    // 1. fused convert (x, clusters) + weight transpose
    prep_kernel<<<dim3(5888), dim3(256), 0, stream>>>(
        x, x_bf, (B_ * N_ * D_) / 8, clusters, cl_bf,
        Wq, Wkv, Wout, WqT, WkvT, WoutT);
    // 2. fused kv + q projections (q rides the kv tail)
    gemm_kvq_kernel<<<dim3(1056), dim3(256), 0, stream>>>(
        x_bf, WkvT, kvb, cl_bf, WqT, qb);
    // 3. attention partials (4 waves x 128 rows, round-12 best)
    attn_kernel<<<dim3(NCHUNK, H_, B_), dim3(256), 0, stream>>>(
        qb, kvb, out_part, ts_part);
    // 4. reduce + normalize + token_sizes
    reduce_kernel<<<dim3(B_ * NC_), dim3(256), 0, stream>>>(
        out_part, ts_part, out_mid, tok);
    // 5. out = out_mid @ Wout (fp32)
    gemm_out_kernel<<<dim3(D_ / 128, (B_ * NC_) / 128), dim3(256), 0, stream>>>(
        out_mid, WoutT, (float*)d_out);
}